// Round 1
// baseline (1913.066 us; speedup 1.0000x reference)
//
#include <hip/hip_runtime.h>

// Problem constants (B, nf, D, H, W) = (4, 48, 12, 56, 56), fp32 throughout.
constexpr int B_ = 4, C_ = 48, D_ = 12, H_ = 56, W_ = 56;
constexpr int DHW_ = D_ * H_ * W_;        // 37632
constexpr int NLOC_ = B_ * DHW_;          // 150528 (multiple of 256: 588 blocks)
constexpr int OFFC_ = 54;                 // 27 taps x 2 (dh, dw)

// Repack weights [OC][48][3][3][3] -> [27][48][OC] so the hot loops read
// wave-uniform contiguous scalars (s_load_dwordx16 broadcast, no LDS).
__global__ void __launch_bounds__(256) repack_w_kernel(const float* __restrict__ w,
                                                       float* __restrict__ wr, int OC) {
    int i = blockIdx.x * 256 + threadIdx.x;
    int total = OC * 48 * 27;
    if (i >= total) return;
    int k  = i % 27;
    int c  = (i / 27) % 48;
    int oc = i / (27 * 48);
    wr[(k * 48 + c) * OC + oc] = w[i];
}

// Plain 3x3x3 conv (zero pad 1) producing the 54 offset channels.
// One thread = one spatial location, all 54 output channels in registers.
__global__ void __launch_bounds__(256) offconv_kernel(
    const float* __restrict__ x,      // [B][48][D][H][W]
    const float* __restrict__ wr,     // [27][48][54] repacked
    const float* __restrict__ bo,     // [54]
    float* __restrict__ off) {        // [B][54][D][H][W]
    int loc = blockIdx.x * 256 + threadIdx.x;
    int w = loc % W_; int t = loc / W_;
    int h = t % H_;   t /= H_;
    int d = t % D_;   int b = t / D_;

    float acc[OFFC_];
#pragma unroll
    for (int oc = 0; oc < OFFC_; ++oc) acc[oc] = bo[oc];

    const float* xb = x + (size_t)b * (C_ * DHW_);
#pragma unroll 1
    for (int kd = -1; kd <= 1; ++kd) {
        int pd = d + kd;
        if (pd < 0 || pd >= D_) continue;
#pragma unroll 1
        for (int kh = -1; kh <= 1; ++kh) {
            int ph = h + kh;
            if (ph < 0 || ph >= H_) continue;
#pragma unroll 1
            for (int kw = -1; kw <= 1; ++kw) {
                int pw = w + kw;
                if (pw < 0 || pw >= W_) continue;
                int k = ((kd + 1) * 3 + (kh + 1)) * 3 + (kw + 1);
                const float* xp = xb + (pd * H_ + ph) * W_ + pw;
                const float* wp = wr + k * (48 * OFFC_);
#pragma unroll 2
                for (int c = 0; c < C_; ++c) {
                    float v = xp[(size_t)c * DHW_];
                    const float* wpc = wp + c * OFFC_;
#pragma unroll
                    for (int oc = 0; oc < OFFC_; ++oc) acc[oc] += v * wpc[oc];
                }
            }
        }
    }
    float* op = off + (size_t)b * (OFFC_ * DHW_) + (d * H_ + h) * W_ + w;
#pragma unroll
    for (int oc = 0; oc < OFFC_; ++oc) op[(size_t)oc * DHW_] = acc[oc];
}

// Deformable conv (HW bilinear, integer D taps, zero pad outside volume).
// One thread = one spatial location, 48 output-channel accumulators.
// LEAKY: apply LeakyReLU(0.1) to result. RESID: add resid (the block input x).
template <int LEAKY, int RESID>
__global__ void __launch_bounds__(256) deform_kernel(
    const float* __restrict__ src,    // [B][48][D][H][W]
    const float* __restrict__ off,    // [B][54][D][H][W] (= [B][27][2][D][H][W])
    const float* __restrict__ wr,     // [27][48][48] repacked
    const float* __restrict__ bias,   // [48]
    const float* __restrict__ resid,  // [B][48][D][H][W] or unused
    float* __restrict__ dst) {        // [B][48][D][H][W]
    int loc = blockIdx.x * 256 + threadIdx.x;
    int w = loc % W_; int t = loc / W_;
    int h = t % H_;   t /= H_;
    int d = t % D_;   int b = t / D_;

    float acc[C_];
#pragma unroll
    for (int oc = 0; oc < C_; ++oc) acc[oc] = bias[oc];

    const float* sb = src + (size_t)b * (C_ * DHW_);
    const float* ob = off + (size_t)b * (OFFC_ * DHW_) + (d * H_ + h) * W_ + w;

#pragma unroll 1
    for (int k = 0; k < 27; ++k) {
        int kd = k / 9 - 1, kh = (k / 3) % 3 - 1, kw = k % 3 - 1;
        int pd = d + kd;
        bool vd = (pd >= 0) & (pd < D_);
        int pdc = min(max(pd, 0), D_ - 1);

        float odh = ob[(size_t)(2 * k + 0) * DHW_];
        float odw = ob[(size_t)(2 * k + 1) * DHW_];
        float phf = (float)(h + kh) + odh;
        float pwf = (float)(w + kw) + odw;
        float h0f = floorf(phf), w0f = floorf(pwf);
        float th = phf - h0f, tw = pwf - w0f;
        int h0 = (int)h0f, w0 = (int)w0f;

        int idx[4];
        float cw[4];
#pragma unroll
        for (int dh = 0; dh < 2; ++dh) {
            int hh = h0 + dh;
            bool vh = vd & (hh >= 0) & (hh < H_);
            int hhc = min(max(hh, 0), H_ - 1);
            float wh = dh ? th : 1.0f - th;
#pragma unroll
            for (int dw = 0; dw < 2; ++dw) {
                int ww = w0 + dw;
                bool v = vh & (ww >= 0) & (ww < W_);
                int wwc = min(max(ww, 0), W_ - 1);
                float wwt = dw ? tw : 1.0f - tw;
                idx[dh * 2 + dw] = (pdc * H_ + hhc) * W_ + wwc;
                cw[dh * 2 + dw] = v ? wh * wwt : 0.0f;
            }
        }

        const float* wp = wr + k * (48 * C_);
#pragma unroll 2
        for (int c = 0; c < C_; ++c) {
            const float* sc = sb + (size_t)c * DHW_;
            float v = cw[0] * sc[idx[0]] + cw[1] * sc[idx[1]] +
                      cw[2] * sc[idx[2]] + cw[3] * sc[idx[3]];
            const float* wpc = wp + c * C_;
#pragma unroll
            for (int oc = 0; oc < C_; ++oc) acc[oc] += v * wpc[oc];
        }
    }

    size_t obase = (size_t)b * (C_ * DHW_) + (size_t)(d * H_ + h) * W_ + w;
#pragma unroll
    for (int oc = 0; oc < C_; ++oc) {
        float v = acc[oc];
        if (LEAKY) v = (v >= 0.0f) ? v : 0.1f * v;
        if (RESID) v += resid[obase + (size_t)oc * DHW_];
        dst[obase + (size_t)oc * DHW_] = v;
    }
}

extern "C" void kernel_launch(void* const* d_in, const int* in_sizes, int n_in,
                              void* d_out, int out_size, void* d_ws, size_t ws_size,
                              hipStream_t stream) {
    const float* x      = (const float*)d_in[0];
    const float* w_off0 = (const float*)d_in[1];
    const float* b_off0 = (const float*)d_in[2];
    const float* w0     = (const float*)d_in[3];
    const float* b0     = (const float*)d_in[4];
    const float* w_off1 = (const float*)d_in[5];
    const float* b_off1 = (const float*)d_in[6];
    const float* w1     = (const float*)d_in[7];
    const float* b1     = (const float*)d_in[8];
    float* out = (float*)d_out;

    // Workspace layout (floats): off (54*150528) | h (48*150528/... = B*C*DHW) | wr_off | wr_conv
    float* off_buf = (float*)d_ws;                               // 8,128,512 f
    float* h_buf   = off_buf + (size_t)OFFC_ * NLOC_;            // 7,225,344 f
    float* wr_off  = h_buf + (size_t)C_ * NLOC_;                 // 69,984 f
    float* wr_conv = wr_off + 27 * 48 * OFFC_;                   // 62,208 f

    dim3 blk(256);
    int nblocks = NLOC_ / 256;  // 588

    // --- layer 0 ---
    repack_w_kernel<<<(OFFC_ * 48 * 27 + 255) / 256, blk, 0, stream>>>(w_off0, wr_off, OFFC_);
    offconv_kernel<<<nblocks, blk, 0, stream>>>(x, wr_off, b_off0, off_buf);
    repack_w_kernel<<<(C_ * 48 * 27 + 255) / 256, blk, 0, stream>>>(w0, wr_conv, C_);
    deform_kernel<1, 0><<<nblocks, blk, 0, stream>>>(x, off_buf, wr_conv, b0, nullptr, h_buf);

    // --- layer 1 ---
    repack_w_kernel<<<(OFFC_ * 48 * 27 + 255) / 256, blk, 0, stream>>>(w_off1, wr_off, OFFC_);
    offconv_kernel<<<nblocks, blk, 0, stream>>>(h_buf, wr_off, b_off1, off_buf);
    repack_w_kernel<<<(C_ * 48 * 27 + 255) / 256, blk, 0, stream>>>(w1, wr_conv, C_);
    deform_kernel<0, 1><<<nblocks, blk, 0, stream>>>(h_buf, off_buf, wr_conv, b1, x, out);
}